// Round 3
// baseline (1195.773 us; speedup 1.0000x reference)
//
#include <hip/hip_runtime.h>
#include <hip/hip_bf16.h>

#define MROWS 4096      // B*T
#define KDIM 1024       // H
#define NVOCAB 32000    // V
#define BM 256
#define BN 256
#define BK 64
#define NTILES (NVOCAB / BN)   // 125
#define MTILES (MROWS / BM)    // 16
#define KT (KDIM / BK)         // 16
#define BETA 0.1f

typedef __attribute__((ext_vector_type(8))) short s8v;
typedef __attribute__((ext_vector_type(16))) float f16v;

__device__ inline void gload16(const void* g, void* l) {
  __builtin_amdgcn_global_load_lds(
      (const __attribute__((address_space(1))) void*)g,
      (__attribute__((address_space(3))) void*)l, 16, 0, 0);
}

__device__ inline unsigned bf16pair(float lo, float hi) {
  unsigned a = __float_as_uint(lo), b = __float_as_uint(hi);
  a = (a + 0x7FFFu + ((a >> 16) & 1u)) >> 16;
  b = (b + 0x7FFFu + ((b >> 16) & 1u)) >> 16;
  return a | (b << 16);
}

// fused fp32 -> bf16 (RNE) for all 4 tensors, grid-stride, 16B/load
__global__ void cvt_all(const float4* __restrict__ x, const float4* __restrict__ rx,
                        const float4* __restrict__ W, const float4* __restrict__ rW,
                        uint4* __restrict__ xb, uint4* __restrict__ rxb,
                        uint4* __restrict__ Wb, uint4* __restrict__ rWb) {
  const int NX = MROWS * KDIM / 8;      // 524288
  const int NW = NVOCAB * KDIM / 8;     // 4096000
  const int total = 2 * NX + 2 * NW;
  for (int i = blockIdx.x * 256 + threadIdx.x; i < total; i += gridDim.x * 256) {
    const float4* s; uint4* d; int j;
    if (i < NX)               { s = x;  d = xb;  j = i; }
    else if (i < 2 * NX)      { s = rx; d = rxb; j = i - NX; }
    else if (i < 2 * NX + NW) { s = W;  d = Wb;  j = i - 2 * NX; }
    else                      { s = rW; d = rWb; j = i - 2 * NX - NW; }
    float4 a = s[2 * j], b = s[2 * j + 1];
    uint4 o;
    o.x = bf16pair(a.x, a.y);
    o.y = bf16pair(a.z, a.w);
    o.z = bf16pair(b.x, b.y);
    o.w = bf16pair(b.z, b.w);
    d[j] = o;
  }
}

// 256x256 GEMM tile (32x32x16 MFMA) + fused per-tile logsumexp + target gather.
// LDS layout is FRAGMENT-CONTIGUOUS: per K-tile, matrix tile (256 rows x 64 k)
// is stored as 32 blocks of 1024B; block (g,ks) holds rows g*32..+31, k ks*16..+15,
// with lane p owning row g*32+(p&31), k-bytes [ks*32+(p>>5)*16 .. +16).
// => every ds_read_b128 is uniform-base + imm offset, stride-1, conflict-free.
// grid = (2000, 2 models), block = 512 (8 waves, 2x4, each 128x64 output)
__global__ __launch_bounds__(512, 2) void gemm_lse(
    const __hip_bfloat16* __restrict__ xb, const __hip_bfloat16* __restrict__ rxb,
    const __hip_bfloat16* __restrict__ Wb, const __hip_bfloat16* __restrict__ rWb,
    const int* __restrict__ y,
    float2* __restrict__ partials,  // [2][NTILES][MROWS]
    float* __restrict__ tgt)        // [2][MROWS]
{
  const int bid = blockIdx.x;       // 0..1999
  const int bz  = blockIdx.y;       // model
  // XCD chunking: each XCD sweeps 4-mtile bands across ntiles (W panel reuse)
  const int lin   = (bid & 7) * 250 + (bid >> 3);
  const int mg    = lin / 500;
  const int rem   = lin % 500;
  const int ntile = rem >> 2;
  const int mtile = mg * 4 + (rem & 3);
  const int m0 = mtile * BM, n0 = ntile * BN;

  const __hip_bfloat16* A  = bz ? rxb : xb;
  const __hip_bfloat16* Bw = bz ? rWb : Wb;

  const int tid = threadIdx.x;
  const int lane = tid & 63;
  const int w = tid >> 6;            // 0..7
  const int wr = w >> 2, wc = w & 3; // 2 x 4 wave grid
  const int l31 = lane & 31, hi = lane >> 5;
  const int lane16 = lane * 16;

  __shared__ __align__(16) short As[2][BM * BK];
  __shared__ __align__(16) short Bs[2][BM * BK];
  __shared__ int ys[BM];
  __shared__ float redM[4][BM];
  __shared__ float redS[4][BM];

  if (tid < BM) ys[tid] = y[m0 + tid];

  f16v acc[4][2];
#pragma unroll
  for (int i = 0; i < 4; ++i)
#pragma unroll
    for (int j = 0; j < 2; ++j) acc[i][j] = (f16v)(0.f);

  // staging source map: chunk c = j*512+tid -> LDS bytes [c*16, c*16+16)
  // block b = c>>6 (g=b>>2, ks=b&3), pos p = c&63:
  //   row = g*32 + (p&31), col elems = ks*16 + (p>>5)*8
  const __hip_bfloat16* srcA[4];
  const __hip_bfloat16* srcB[4];
#pragma unroll
  for (int j = 0; j < 4; ++j) {
    int c = j * 512 + tid;
    int p = c & 63, b = c >> 6;
    int row = (b >> 2) * 32 + (p & 31);
    int col = (b & 3) * 16 + (p >> 5) * 8;
    srcA[j] = A  + (size_t)(m0 + row) * KDIM + col;
    srcB[j] = Bw + (size_t)(n0 + row) * KDIM + col;
  }

#define STAGE(buf)                                                   \
  {                                                                  \
    _Pragma("unroll")                                                \
    for (int j = 0; j < 4; ++j) {                                    \
      gload16(srcA[j], &As[buf][(j * 512 + tid) * 8]);               \
      gload16(srcB[j], &Bs[buf][(j * 512 + tid) * 8]);               \
      srcA[j] += BK; srcB[j] += BK;                                  \
    }                                                                \
  }

#define COMPUTE(cur)                                                        \
  {                                                                         \
    const char* Sa = ((const char*)As[cur]) + wr * 16384 + lane16;          \
    const char* Sb = ((const char*)Bs[cur]) + wc * 8192 + lane16;           \
    _Pragma("unroll")                                                       \
    for (int ks = 0; ks < 4; ++ks) {                                        \
      s8v af[4], bf[2];                                                     \
      _Pragma("unroll")                                                     \
      for (int mi = 0; mi < 4; ++mi)                                        \
        af[mi] = *(const s8v*)(Sa + (mi * 4 + ks) * 1024);                  \
      _Pragma("unroll")                                                     \
      for (int ni = 0; ni < 2; ++ni)                                        \
        bf[ni] = *(const s8v*)(Sb + (ni * 4 + ks) * 1024);                  \
      __builtin_amdgcn_s_setprio(1);                                        \
      _Pragma("unroll")                                                     \
      for (int mi = 0; mi < 4; ++mi)                                        \
        _Pragma("unroll")                                                   \
        for (int ni = 0; ni < 2; ++ni)                                      \
          acc[mi][ni] = __builtin_amdgcn_mfma_f32_32x32x16_bf16(            \
              af[mi], bf[ni], acc[mi][ni], 0, 0, 0);                        \
      __builtin_amdgcn_s_setprio(0);                                        \
    }                                                                       \
  }

  // prologue: tile 0 staged into buf0
  STAGE(0);
  __syncthreads();

  for (int tp = 0; tp < KT; tp += 2) {
    if (tp + 1 < KT) STAGE(1);   // prefetch next tile, 4 ks-phases of cover
    COMPUTE(0);
    __syncthreads();
    if (tp + 2 < KT) STAGE(0);
    COMPUTE(1);
    __syncthreads();
  }

  // Epilogue: per-row (max, sumexp) over this block's 256 cols + target gather.
  // 32x32 D layout: col = lane&31, row = (r&3) + 8*(r>>2) + 4*(lane>>5)
#pragma unroll
  for (int mi = 0; mi < 4; ++mi) {
#pragma unroll
    for (int r = 0; r < 16; ++r) {
      float v0 = acc[mi][0][r], v1 = acc[mi][1][r];
      float mx = fmaxf(v0, v1);
#pragma unroll
      for (int d = 1; d < 32; d <<= 1) mx = fmaxf(mx, __shfl_xor(mx, d));
      float ex = __expf(v0 - mx) + __expf(v1 - mx);
#pragma unroll
      for (int d = 1; d < 32; d <<= 1) ex += __shfl_xor(ex, d);
      int rowInBlock = wr * 128 + mi * 32 + (r & 3) + 8 * (r >> 2) + 4 * hi;
      if (l31 == 0) { redM[wc][rowInBlock] = mx; redS[wc][rowInBlock] = ex; }
      int yv = ys[rowInBlock];
      int cl = yv - (n0 + wc * 64);
      if (cl >= 0 && cl < 64 && (cl & 31) == l31)
        tgt[(size_t)bz * MROWS + m0 + rowInBlock] = (cl >> 5) ? v1 : v0;
    }
  }
  __syncthreads();
  if (tid < BM) {
    float M = redM[0][tid], S = redS[0][tid];
#pragma unroll
    for (int c = 1; c < 4; ++c) {
      float m2 = redM[c][tid], s2 = redS[c][tid];
      float Mn = fmaxf(M, m2);
      S = S * __expf(M - Mn) + s2 * __expf(m2 - Mn);
      M = Mn;
    }
    partials[((size_t)bz * NTILES + ntile) * MROWS + m0 + tid] = make_float2(M, S);
  }
#undef STAGE
#undef COMPUTE
}

// merge partials per row -> lse -> per-example mean target logp
__global__ void rowred(const float2* __restrict__ partials, const float* __restrict__ tgt,
                       const int* __restrict__ y, float* __restrict__ logps) {
  const int model = blockIdx.x >> 2;
  const int b = blockIdx.x & 3;
  const int tid = threadIdx.x;
  float sum = 0.f, cnt = 0.f;
  for (int t = tid; t < 1024; t += 256) {
    const int row = b * 1024 + t;
    float M = -INFINITY, S = 0.f;
    for (int j = 0; j < NTILES; ++j) {
      float2 v = partials[((size_t)model * NTILES + j) * MROWS + row];
      float Mn = fmaxf(M, v.x);
      S = S * __expf(M - Mn) + v.y * __expf(v.x - Mn);
      M = Mn;
    }
    int yv = y[row];
    if (yv != -100) {
      sum += tgt[(size_t)model * MROWS + row] - (M + __logf(S));
      cnt += 1.f;
    }
  }
  __shared__ float sS[4], sC[4];
#pragma unroll
  for (int d = 1; d < 64; d <<= 1) { sum += __shfl_xor(sum, d); cnt += __shfl_xor(cnt, d); }
  int w = tid >> 6;
  if ((tid & 63) == 0) { sS[w] = sum; sC[w] = cnt; }
  __syncthreads();
  if (tid == 0) {
    float s = 0.f, c = 0.f;
    for (int i = 0; i < 4; ++i) { s += sS[i]; c += sC[i]; }
    logps[blockIdx.x] = s / c;
  }
}

__global__ void finalk(const float* __restrict__ logps, const int* __restrict__ pref,
                       float* __restrict__ out) {
  if (threadIdx.x == 0 && blockIdx.x == 0) {
    float acc = 0.f;
    for (int b = 0; b < 4; ++b) {
      float lr = logps[b] - logps[4 + b];   // policy - ref
      float z = BETA * lr;
      float sig = 1.f / (1.f + __expf(-z));
      acc += (pref[b] != 0) ? (1.f - sig) : sig;
    }
    out[0] = acc * 0.25f;
  }
}

extern "C" void kernel_launch(void* const* d_in, const int* in_sizes, int n_in,
                              void* d_out, int out_size, void* d_ws, size_t ws_size,
                              hipStream_t stream) {
  const float* x    = (const float*)d_in[0];
  const float* rx   = (const float*)d_in[1];
  const int*   y    = (const int*)d_in[2];
  const int*   pref = (const int*)d_in[3];
  const float* W    = (const float*)d_in[4];
  const float* rW   = (const float*)d_in[5];
  float* out = (float*)d_out;

  char* ws = (char*)d_ws;
  const size_t SZ_X = (size_t)MROWS * KDIM * 2;        // 8,388,608
  const size_t SZ_W = (size_t)NVOCAB * KDIM * 2;       // 65,536,000
  __hip_bfloat16* xb   = (__hip_bfloat16*)(ws);
  __hip_bfloat16* rxb  = (__hip_bfloat16*)(ws + SZ_X);
  __hip_bfloat16* Wb   = (__hip_bfloat16*)(ws + 2 * SZ_X);
  __hip_bfloat16* rWb  = (__hip_bfloat16*)(ws + 2 * SZ_X + SZ_W);
  float2* partials = (float2*)(ws + 2 * SZ_X + 2 * SZ_W);
  float*  tgt      = (float*)(ws + 2 * SZ_X + 2 * SZ_W + (size_t)2 * NTILES * MROWS * 8);
  float*  logps    = (float*)(ws + 2 * SZ_X + 2 * SZ_W + (size_t)2 * NTILES * MROWS * 8 + 2 * MROWS * 4);

  cvt_all<<<dim3(2048), 256, 0, stream>>>((const float4*)x, (const float4*)rx,
                                          (const float4*)W, (const float4*)rW,
                                          (uint4*)xb, (uint4*)rxb, (uint4*)Wb, (uint4*)rWb);

  gemm_lse<<<dim3(2000, 2), 512, 0, stream>>>(xb, rxb, Wb, rWb, y, partials, tgt);
  rowred<<<dim3(8), 256, 0, stream>>>(partials, tgt, y, logps);
  finalk<<<dim3(1), 64, 0, stream>>>(logps, pref, out);
}

// Round 5
// 1034.230 us; speedup vs baseline: 1.1562x; 1.1562x over previous
//
#include <hip/hip_runtime.h>
#include <hip/hip_bf16.h>

#define MROWS 4096      // B*T
#define KDIM 1024       // H
#define NVOCAB 32000    // V
#define BM 256
#define BN 256
#define BK 32
#define NTILES (NVOCAB / BN)   // 125
#define KT (KDIM / BK)         // 32
#define BETA 0.1f

typedef __attribute__((ext_vector_type(8))) short s8v;
typedef __attribute__((ext_vector_type(4))) float f4v;

__device__ inline void gload16(const void* g, void* l) {
  __builtin_amdgcn_global_load_lds(
      (const __attribute__((address_space(1))) void*)g,
      (__attribute__((address_space(3))) void*)l, 16, 0, 0);
}

__device__ inline unsigned bf16pair(float lo, float hi) {
  unsigned a = __float_as_uint(lo), b = __float_as_uint(hi);
  a = (a + 0x7FFFu + ((a >> 16) & 1u)) >> 16;
  b = (b + 0x7FFFu + ((b >> 16) & 1u)) >> 16;
  return a | (b << 16);
}

// fused fp32 -> bf16 (RNE) for all 4 tensors, grid-stride, 16B/load
__global__ void cvt_all(const float4* __restrict__ x, const float4* __restrict__ rx,
                        const float4* __restrict__ W, const float4* __restrict__ rW,
                        uint4* __restrict__ xb, uint4* __restrict__ rxb,
                        uint4* __restrict__ Wb, uint4* __restrict__ rWb) {
  const int NX = MROWS * KDIM / 8;      // 524288
  const int NW = NVOCAB * KDIM / 8;     // 4096000
  const int total = 2 * NX + 2 * NW;
  for (int i = blockIdx.x * 256 + threadIdx.x; i < total; i += gridDim.x * 256) {
    const float4* s; uint4* d; int j;
    if (i < NX)               { s = x;  d = xb;  j = i; }
    else if (i < 2 * NX)      { s = rx; d = rxb; j = i - NX; }
    else if (i < 2 * NX + NW) { s = W;  d = Wb;  j = i - 2 * NX; }
    else                      { s = rW; d = rWb; j = i - 2 * NX - NW; }
    float4 a = s[2 * j], b = s[2 * j + 1];
    uint4 o;
    o.x = bf16pair(a.x, a.y);
    o.y = bf16pair(a.z, a.w);
    o.z = bf16pair(b.x, b.y);
    o.w = bf16pair(b.z, b.w);
    d[j] = o;
  }
}

// 256x256 GEMM tile, BK=32, 3-slot LDS rotation, counted vmcnt(4) pipeline.
// LDS layout fragment-contiguous: K-tile (256 rows x 32 k) = 16 blocks of 1024B;
// block g holds rows g*16..+15; lane l of a block owns row (l&15), k (l>>4)*8..+8
// => ds_read_b128 at uniform base + lane*16 + imm, stride-1, conflict-free.
// grid = (2000, 2 models), block = 512 (8 waves, 2x4, each 128x64 output)
__global__ __launch_bounds__(512, 2) void gemm_lse(
    const __hip_bfloat16* __restrict__ xb, const __hip_bfloat16* __restrict__ rxb,
    const __hip_bfloat16* __restrict__ Wb, const __hip_bfloat16* __restrict__ rWb,
    const int* __restrict__ y,
    float2* __restrict__ partials,  // [2][NTILES][MROWS]
    float* __restrict__ tgt)        // [2][MROWS]
{
  const int bid = blockIdx.x;       // 0..1999
  const int bz  = blockIdx.y;       // model
  // XCD chunking: each XCD sweeps 4-mtile bands across ntiles (W panel reuse)
  const int lin   = (bid & 7) * 250 + (bid >> 3);
  const int mg    = lin / 500;
  const int rem   = lin % 500;
  const int ntile = rem >> 2;
  const int mtile = mg * 4 + (rem & 3);
  const int m0 = mtile * BM, n0 = ntile * BN;

  const __hip_bfloat16* A  = bz ? rxb : xb;
  const __hip_bfloat16* Bw = bz ? rWb : Wb;

  const int tid = threadIdx.x;
  const int lane = tid & 63;
  const int w = tid >> 6;            // 0..7
  const int wr = w >> 2, wc = w & 3; // 2 x 4 wave grid
  const int l15 = lane & 15, l4 = lane >> 4;

  __shared__ __align__(16) short As[3][BM * BK];   // 3 x 16 KB
  __shared__ __align__(16) short Bs[3][BN * BK];   // 3 x 16 KB
  __shared__ int ys[BM];
  __shared__ float redM[4][BM];
  __shared__ float redS[4][BM];

  if (tid < BM) ys[tid] = y[m0 + tid];

  f4v acc[8][4];
#pragma unroll
  for (int i = 0; i < 8; ++i)
#pragma unroll
    for (int j = 0; j < 4; ++j) acc[i][j] = (f4v){0.f, 0.f, 0.f, 0.f};

  // staging source: thread covers chunks tid and tid+512 of each K-tile:
  //   chunk c: row (c>>6)*16 + (c&15), col ((c>>4)&3)*8; chunk tid+512 = +128 rows
  //   chunk c -> LDS SHORT index c*8 (byte c*16); tid+512 -> tid*8 + 4096 shorts
  const int prow = (tid >> 6) * 16 + (tid & 15);
  const int pcol = ((tid >> 4) & 3) * 8;
  const __hip_bfloat16* sA = A  + (size_t)(m0 + prow) * KDIM + pcol;
  const __hip_bfloat16* sB = Bw + (size_t)(n0 + prow) * KDIM + pcol;
  const size_t rstep = (size_t)128 * KDIM;

  // ---- prologue: stage K-tiles 0,1 -> slots 0,1; wait oldest 4 (tile 0) ----
  gload16(sA,             &As[0][tid * 8]);
  gload16(sA + rstep,     &As[0][tid * 8 + 4096]);
  gload16(sB,             &Bs[0][tid * 8]);
  gload16(sB + rstep,     &Bs[0][tid * 8 + 4096]);
  gload16(sA + 32,         &As[1][tid * 8]);
  gload16(sA + 32 + rstep, &As[1][tid * 8 + 4096]);
  gload16(sB + 32,         &Bs[1][tid * 8]);
  gload16(sB + 32 + rstep, &Bs[1][tid * 8 + 4096]);
  asm volatile("s_waitcnt vmcnt(4)" ::: "memory");
  __builtin_amdgcn_s_barrier();
  __builtin_amdgcn_sched_barrier(0);

  int slot = 0;
  int koff = 64;   // K-offset (elems) of the tile being staged (t+2)

  // Group t: 2 phases x 16 MFMA on slot t%3; stage tile t+2 into slot (t+2)%3;
  // trailing counted vmcnt(4) validates tile t+1 (ledger: outstanding at trail =
  // {A(t+1),B(t+1),A(t+2),B(t+2)}; vmcnt(4) retires the oldest 4).
#define GROUP_BODY(DOSTAGE, TRAILCNT, DO_TRAIL)                               \
  {                                                                           \
    const int sslot = (slot == 0) ? 2 : slot - 1; /* == (slot+2)%3 */         \
    const char* bA = (const char*)(&As[slot][0]) + wr * 8192 + lane * 16;     \
    const char* bB = (const char*)(&Bs[slot][0]) + wc * 4096 + lane * 16;     \
    s8v af[4], bf[4];                                                         \
    _Pragma("unroll")                                                         \
    for (int mi = 0; mi < 4; ++mi) af[mi] = *(const s8v*)(bA + mi * 1024);    \
    _Pragma("unroll")                                                         \
    for (int ni = 0; ni < 4; ++ni) bf[ni] = *(const s8v*)(bB + ni * 1024);    \
    if (DOSTAGE) {                                                            \
      gload16(sA + koff,         &As[sslot][tid * 8]);                        \
      gload16(sA + koff + rstep, &As[sslot][tid * 8 + 4096]);                 \
    }                                                                         \
    __builtin_amdgcn_s_barrier();                                             \
    asm volatile("s_waitcnt lgkmcnt(0)" ::: "memory");                        \
    __builtin_amdgcn_sched_barrier(0);                                        \
    __builtin_amdgcn_s_setprio(1);                                            \
    _Pragma("unroll")                                                         \
    for (int mi = 0; mi < 4; ++mi)                                            \
      _Pragma("unroll")                                                       \
      for (int ni = 0; ni < 4; ++ni)                                          \
        acc[mi][ni] = __builtin_amdgcn_mfma_f32_16x16x32_bf16(                \
            af[mi], bf[ni], acc[mi][ni], 0, 0, 0);                            \
    __builtin_amdgcn_s_setprio(0);                                            \
    _Pragma("unroll")                                                         \
    for (int mi = 0; mi < 4; ++mi) af[mi] = *(const s8v*)(bA + (4 + mi) * 1024);\
    if (DOSTAGE) {                                                            \
      gload16(sB + koff,         &Bs[sslot][tid * 8]);                        \
      gload16(sB + koff + rstep, &Bs[sslot][tid * 8 + 4096]);                 \
    }                                                                         \
    __builtin_amdgcn_s_barrier();                                             \
    asm volatile("s_waitcnt lgkmcnt(0)" ::: "memory");                        \
    __builtin_amdgcn_sched_barrier(0);                                        \
    __builtin_amdgcn_s_setprio(1);                                            \
    _Pragma("unroll")                                                         \
    for (int mi = 0; mi < 4; ++mi)                                            \
      _Pragma("unroll")                                                       \
      for (int ni = 0; ni < 4; ++ni)                                          \
        acc[4 + mi][ni] = __builtin_amdgcn_mfma_f32_16x16x32_bf16(            \
            af[mi], bf[ni], acc[4 + mi][ni], 0, 0, 0);                        \
    __builtin_amdgcn_s_setprio(0);                                            \
    if (DO_TRAIL) {                                                           \
      asm volatile("s_waitcnt " TRAILCNT ::: "memory");                       \
      __builtin_amdgcn_s_barrier();                                           \
      __builtin_amdgcn_sched_barrier(0);                                      \
    }                                                                         \
    if (DOSTAGE) koff += BK;                                                  \
    slot = (slot == 2) ? 0 : slot + 1;                                        \
  }

#pragma unroll 1
  for (int t = 0; t < KT - 2; ++t) GROUP_BODY(1, "vmcnt(4)", 1)
  GROUP_BODY(0, "vmcnt(0)", 1)   // group 30: tail, full drain once
  GROUP_BODY(0, "vmcnt(0)", 0)   // group 31: last, no trail needed
#undef GROUP_BODY

  // Epilogue: per-row (max, sumexp) over this block's 256 cols + target gather.
  // 16x16 D layout: row = wr*128 + mi*16 + l4*4 + r, col = wc*64 + ni*16 + l15
#pragma unroll
  for (int mi = 0; mi < 8; ++mi) {
#pragma unroll
    for (int r = 0; r < 4; ++r) {
      float v0 = acc[mi][0][r], v1 = acc[mi][1][r], v2 = acc[mi][2][r], v3 = acc[mi][3][r];
      float mx = fmaxf(fmaxf(v0, v1), fmaxf(v2, v3));
#pragma unroll
      for (int d = 1; d < 16; d <<= 1) mx = fmaxf(mx, __shfl_xor(mx, d));
      float ex = __expf(v0 - mx) + __expf(v1 - mx) + __expf(v2 - mx) + __expf(v3 - mx);
#pragma unroll
      for (int d = 1; d < 16; d <<= 1) ex += __shfl_xor(ex, d);
      int rowInBlock = wr * 128 + mi * 16 + l4 * 4 + r;
      if (l15 == 0) { redM[wc][rowInBlock] = mx; redS[wc][rowInBlock] = ex; }
      int yv = ys[rowInBlock];
      int cl = yv - (n0 + wc * 64);
      if (cl >= 0 && cl < 64 && (cl & 15) == l15) {
        int ni = cl >> 4;
        float tv = ni == 0 ? v0 : ni == 1 ? v1 : ni == 2 ? v2 : v3;
        tgt[(size_t)bz * MROWS + m0 + rowInBlock] = tv;
      }
    }
  }
  __syncthreads();
  if (tid < BM) {
    float M = redM[0][tid], S = redS[0][tid];
#pragma unroll
    for (int c = 1; c < 4; ++c) {
      float m2 = redM[c][tid], s2 = redS[c][tid];
      float Mn = fmaxf(M, m2);
      S = S * __expf(M - Mn) + s2 * __expf(m2 - Mn);
      M = Mn;
    }
    partials[((size_t)bz * NTILES + ntile) * MROWS + m0 + tid] = make_float2(M, S);
  }
}

// merge partials per row -> lse -> per-example mean target logp
__global__ void rowred(const float2* __restrict__ partials, const float* __restrict__ tgt,
                       const int* __restrict__ y, float* __restrict__ logps) {
  const int model = blockIdx.x >> 2;
  const int b = blockIdx.x & 3;
  const int tid = threadIdx.x;
  float sum = 0.f, cnt = 0.f;
  for (int t = tid; t < 1024; t += 256) {
    const int row = b * 1024 + t;
    float M = -INFINITY, S = 0.f;
    for (int j = 0; j < NTILES; ++j) {
      float2 v = partials[((size_t)model * NTILES + j) * MROWS + row];
      float Mn = fmaxf(M, v.x);
      S = S * __expf(M - Mn) + v.y * __expf(v.x - Mn);
      M = Mn;
    }
    int yv = y[row];
    if (yv != -100) {
      sum += tgt[(size_t)model * MROWS + row] - (M + __logf(S));
      cnt += 1.f;
    }
  }
  __shared__ float sS[4], sC[4];
#pragma unroll
  for (int d = 1; d < 64; d <<= 1) { sum += __shfl_xor(sum, d); cnt += __shfl_xor(cnt, d); }
  int w = tid >> 6;
  if ((tid & 63) == 0) { sS[w] = sum; sC[w] = cnt; }
  __syncthreads();
  if (tid == 0) {
    float s = 0.f, c = 0.f;
    for (int i = 0; i < 4; ++i) { s += sS[i]; c += sC[i]; }
    logps[blockIdx.x] = s / c;
  }
}

__global__ void finalk(const float* __restrict__ logps, const int* __restrict__ pref,
                       float* __restrict__ out) {
  if (threadIdx.x == 0 && blockIdx.x == 0) {
    float acc = 0.f;
    for (int b = 0; b < 4; ++b) {
      float lr = logps[b] - logps[4 + b];   // policy - ref
      float z = BETA * lr;
      float sig = 1.f / (1.f + __expf(-z));
      acc += (pref[b] != 0) ? (1.f - sig) : sig;
    }
    out[0] = acc * 0.25f;
  }
}

extern "C" void kernel_launch(void* const* d_in, const int* in_sizes, int n_in,
                              void* d_out, int out_size, void* d_ws, size_t ws_size,
                              hipStream_t stream) {
  const float* x    = (const float*)d_in[0];
  const float* rx   = (const float*)d_in[1];
  const int*   y    = (const int*)d_in[2];
  const int*   pref = (const int*)d_in[3];
  const float* W    = (const float*)d_in[4];
  const float* rW   = (const float*)d_in[5];
  float* out = (float*)d_out;

  char* ws = (char*)d_ws;
  const size_t SZ_X = (size_t)MROWS * KDIM * 2;        // 8,388,608
  const size_t SZ_W = (size_t)NVOCAB * KDIM * 2;       // 65,536,000
  __hip_bfloat16* xb   = (__hip_bfloat16*)(ws);
  __hip_bfloat16* rxb  = (__hip_bfloat16*)(ws + SZ_X);
  __hip_bfloat16* Wb   = (__hip_bfloat16*)(ws + 2 * SZ_X);
  __hip_bfloat16* rWb  = (__hip_bfloat16*)(ws + 2 * SZ_X + SZ_W);
  float2* partials = (float2*)(ws + 2 * SZ_X + 2 * SZ_W);
  float*  tgt      = (float*)(ws + 2 * SZ_X + 2 * SZ_W + (size_t)2 * NTILES * MROWS * 8);
  float*  logps    = (float*)(ws + 2 * SZ_X + 2 * SZ_W + (size_t)2 * NTILES * MROWS * 8 + 2 * MROWS * 4);

  cvt_all<<<dim3(2048), 256, 0, stream>>>((const float4*)x, (const float4*)rx,
                                          (const float4*)W, (const float4*)rW,
                                          (uint4*)xb, (uint4*)rxb, (uint4*)Wb, (uint4*)rWb);

  gemm_lse<<<dim3(2000, 2), 512, 0, stream>>>(xb, rxb, Wb, rWb, y, partials, tgt);
  rowred<<<dim3(8), 256, 0, stream>>>(partials, tgt, y, logps);
  finalk<<<dim3(1), 64, 0, stream>>>(logps, pref, out);
}

// Round 6
// 833.829 us; speedup vs baseline: 1.4341x; 1.2403x over previous
//
#include <hip/hip_runtime.h>
#include <hip/hip_bf16.h>

#define MROWS 4096      // B*T
#define KDIM 1024       // H
#define NVOCAB 32000    // V
#define BM 256
#define BN 256
#define BK 32
#define NTILES (NVOCAB / BN)   // 125
#define KT (KDIM / BK)         // 32
#define BETA 0.1f

typedef __attribute__((ext_vector_type(8))) short s8v;
typedef __attribute__((ext_vector_type(4))) float f4v;

__device__ inline void gload16(const void* g, void* l) {
  __builtin_amdgcn_global_load_lds(
      (const __attribute__((address_space(1))) void*)g,
      (__attribute__((address_space(3))) void*)l, 16, 0, 0);
}

__device__ inline unsigned bf16pair(float lo, float hi) {
  unsigned a = __float_as_uint(lo), b = __float_as_uint(hi);
  a = (a + 0x7FFFu + ((a >> 16) & 1u)) >> 16;
  b = (b + 0x7FFFu + ((b >> 16) & 1u)) >> 16;
  return a | (b << 16);
}

// fused fp32 -> bf16 (RNE) for all 4 tensors, grid-stride, 16B/load
__global__ void cvt_all(const float4* __restrict__ x, const float4* __restrict__ rx,
                        const float4* __restrict__ W, const float4* __restrict__ rW,
                        uint4* __restrict__ xb, uint4* __restrict__ rxb,
                        uint4* __restrict__ Wb, uint4* __restrict__ rWb) {
  const int NX = MROWS * KDIM / 8;      // 524288
  const int NW = NVOCAB * KDIM / 8;     // 4096000
  const int total = 2 * NX + 2 * NW;
  for (int i = blockIdx.x * 256 + threadIdx.x; i < total; i += gridDim.x * 256) {
    const float4* s; uint4* d; int j;
    if (i < NX)               { s = x;  d = xb;  j = i; }
    else if (i < 2 * NX)      { s = rx; d = rxb; j = i - NX; }
    else if (i < 2 * NX + NW) { s = W;  d = Wb;  j = i - 2 * NX; }
    else                      { s = rW; d = rWb; j = i - 2 * NX - NW; }
    float4 a = s[2 * j], b = s[2 * j + 1];
    uint4 o;
    o.x = bf16pair(a.x, a.y);
    o.y = bf16pair(a.z, a.w);
    o.z = bf16pair(b.x, b.y);
    o.w = bf16pair(b.z, b.w);
    d[j] = o;
  }
}

// 256x256 GEMM tile, BK=32, 3-slot LDS rotation, counted vmcnt(4) trail,
// ONE raw s_barrier per group; all ds_read/MFMA compiler-scheduled (no walls).
// LDS fragment-contiguous: K-tile = 16 blocks of 1024B; block g rows g*16..+15;
// lane l owns row (l&15), k (l>>4)*8..+8 -> ds_read_b128 uniform base + imm.
// grid = (2000, 2 models), block = 512 (8 waves, 2x4, each 128x64 output)
__global__ __launch_bounds__(512, 2) void gemm_lse(
    const __hip_bfloat16* __restrict__ xb, const __hip_bfloat16* __restrict__ rxb,
    const __hip_bfloat16* __restrict__ Wb, const __hip_bfloat16* __restrict__ rWb,
    const int* __restrict__ y,
    float2* __restrict__ partials,  // [2][NTILES][MROWS]
    float* __restrict__ tgt)        // [2][MROWS]
{
  const int bid = blockIdx.x;       // 0..1999
  const int bz  = blockIdx.y;       // model
  // XCD chunking: each XCD sweeps 4-mtile bands across ntiles (W panel reuse)
  const int lin   = (bid & 7) * 250 + (bid >> 3);
  const int mg    = lin / 500;
  const int rem   = lin % 500;
  const int ntile = rem >> 2;
  const int mtile = mg * 4 + (rem & 3);
  const int m0 = mtile * BM, n0 = ntile * BN;

  const __hip_bfloat16* A  = bz ? rxb : xb;
  const __hip_bfloat16* Bw = bz ? rWb : Wb;

  const int tid = threadIdx.x;
  const int lane = tid & 63;
  const int w = tid >> 6;            // 0..7
  const int wr = w >> 2, wc = w & 3; // 2 x 4 wave grid
  const int l15 = lane & 15, l4 = lane >> 4;

  __shared__ __align__(16) short As[3][BM * BK];   // 3 x 16 KB
  __shared__ __align__(16) short Bs[3][BN * BK];   // 3 x 16 KB
  __shared__ int ys[BM];
  __shared__ float redM[4][BM];
  __shared__ float redS[4][BM];

  if (tid < BM) ys[tid] = y[m0 + tid];

  f4v acc[8][4];
#pragma unroll
  for (int i = 0; i < 8; ++i)
#pragma unroll
    for (int j = 0; j < 4; ++j) acc[i][j] = (f4v){0.f, 0.f, 0.f, 0.f};

  // staging source: thread covers chunks tid and tid+512 of each K-tile:
  //   chunk c: block b=c>>6 (rows b*16..+15), pos p=c&63: row b*16+(p&15),
  //   k ((p>>4)&3)*8; LDS short index c*8 (tid+512 -> tid*8+4096)
  const int prow = (tid >> 6) * 16 + (tid & 15);
  const int pcol = ((tid >> 4) & 3) * 8;
  const __hip_bfloat16* sA = A  + (size_t)(m0 + prow) * KDIM + pcol;
  const __hip_bfloat16* sB = Bw + (size_t)(n0 + prow) * KDIM + pcol;
  const size_t rstep = (size_t)128 * KDIM;

  // ---- prologue: stage K-tiles 0,1 -> slots 0,1; wait oldest 4 (tile 0) ----
  gload16(sA,             &As[0][tid * 8]);
  gload16(sA + rstep,     &As[0][tid * 8 + 4096]);
  gload16(sB,             &Bs[0][tid * 8]);
  gload16(sB + rstep,     &Bs[0][tid * 8 + 4096]);
  gload16(sA + 32,         &As[1][tid * 8]);
  gload16(sA + 32 + rstep, &As[1][tid * 8 + 4096]);
  gload16(sB + 32,         &Bs[1][tid * 8]);
  gload16(sB + 32 + rstep, &Bs[1][tid * 8 + 4096]);
  asm volatile("s_waitcnt vmcnt(4) lgkmcnt(0)" ::: "memory");
  __builtin_amdgcn_s_barrier();

  int slot = 0;
  int koff = 64;   // K-offset (elems) of the tile being staged (t+2)

  // Group t: read slot t%3, stage tile t+2 -> (t+2)%3, 32 MFMA (compiler-
  // scheduled), trail = counted vmcnt + barrier validating tile t+1.
#pragma unroll 1
  for (int t = 0; t < KT; ++t) {
    const int sslot = (slot == 0) ? 2 : slot - 1;  // == (slot+2)%3
    const short* Sa = &As[slot][wr * 4096 + lane * 8];
    const short* Sb = &Bs[slot][wc * 2048 + lane * 8];
    s8v af[8], bf[4];
#pragma unroll
    for (int mi = 0; mi < 8; ++mi) af[mi] = *(const s8v*)(Sa + mi * 512);
#pragma unroll
    for (int ni = 0; ni < 4; ++ni) bf[ni] = *(const s8v*)(Sb + ni * 512);
    if (t < KT - 2) {
      gload16(sA + koff,         &As[sslot][tid * 8]);
      gload16(sA + koff + rstep, &As[sslot][tid * 8 + 4096]);
      gload16(sB + koff,         &Bs[sslot][tid * 8]);
      gload16(sB + koff + rstep, &Bs[sslot][tid * 8 + 4096]);
      koff += BK;
    }
#pragma unroll
    for (int mi = 0; mi < 8; ++mi)
#pragma unroll
      for (int ni = 0; ni < 4; ++ni)
        acc[mi][ni] = __builtin_amdgcn_mfma_f32_16x16x32_bf16(
            af[mi], bf[ni], acc[mi][ni], 0, 0, 0);
    if (t < KT - 1) {
      // ledger: entering group, <=4 outstanding (tile t+1); +4 staged here;
      // vmcnt(4) retires tile t+1's 4. Last staging group t=KT-3 also fits;
      // t=KT-2 stages nothing -> only tile KT-1's 4 remain -> vmcnt(0).
      if (t < KT - 2) asm volatile("s_waitcnt vmcnt(4)" ::: "memory");
      else            asm volatile("s_waitcnt vmcnt(0)" ::: "memory");
      __builtin_amdgcn_s_barrier();
    }
    slot = (slot == 2) ? 0 : slot + 1;
  }

  // Epilogue: per-row (max, sumexp) over this block's 256 cols + target gather.
  // 16x16 D layout: row = wr*128 + mi*16 + l4*4 + r, col = wc*64 + ni*16 + l15
#pragma unroll
  for (int mi = 0; mi < 8; ++mi) {
#pragma unroll
    for (int r = 0; r < 4; ++r) {
      float v0 = acc[mi][0][r], v1 = acc[mi][1][r], v2 = acc[mi][2][r], v3 = acc[mi][3][r];
      float mx = fmaxf(fmaxf(v0, v1), fmaxf(v2, v3));
#pragma unroll
      for (int d = 1; d < 16; d <<= 1) mx = fmaxf(mx, __shfl_xor(mx, d));
      float ex = __expf(v0 - mx) + __expf(v1 - mx) + __expf(v2 - mx) + __expf(v3 - mx);
#pragma unroll
      for (int d = 1; d < 16; d <<= 1) ex += __shfl_xor(ex, d);
      int rowInBlock = wr * 128 + mi * 16 + l4 * 4 + r;
      if (l15 == 0) { redM[wc][rowInBlock] = mx; redS[wc][rowInBlock] = ex; }
      int yv = ys[rowInBlock];
      int cl = yv - (n0 + wc * 64);
      if (cl >= 0 && cl < 64 && (cl & 15) == l15) {
        int ni = cl >> 4;
        float tv = ni == 0 ? v0 : ni == 1 ? v1 : ni == 2 ? v2 : v3;
        tgt[(size_t)bz * MROWS + m0 + rowInBlock] = tv;
      }
    }
  }
  __syncthreads();
  if (tid < BM) {
    float M = redM[0][tid], S = redS[0][tid];
#pragma unroll
    for (int c = 1; c < 4; ++c) {
      float m2 = redM[c][tid], s2 = redS[c][tid];
      float Mn = fmaxf(M, m2);
      S = S * __expf(M - Mn) + s2 * __expf(m2 - Mn);
      M = Mn;
    }
    partials[((size_t)bz * NTILES + ntile) * MROWS + m0 + tid] = make_float2(M, S);
  }
}

// merge partials per row -> lse -> per-example mean target logp
__global__ void rowred(const float2* __restrict__ partials, const float* __restrict__ tgt,
                       const int* __restrict__ y, float* __restrict__ logps) {
  const int model = blockIdx.x >> 2;
  const int b = blockIdx.x & 3;
  const int tid = threadIdx.x;
  float sum = 0.f, cnt = 0.f;
  for (int t = tid; t < 1024; t += 256) {
    const int row = b * 1024 + t;
    float M = -INFINITY, S = 0.f;
    for (int j = 0; j < NTILES; ++j) {
      float2 v = partials[((size_t)model * NTILES + j) * MROWS + row];
      float Mn = fmaxf(M, v.x);
      S = S * __expf(M - Mn) + v.y * __expf(v.x - Mn);
      M = Mn;
    }
    int yv = y[row];
    if (yv != -100) {
      sum += tgt[(size_t)model * MROWS + row] - (M + __logf(S));
      cnt += 1.f;
    }
  }
  __shared__ float sS[4], sC[4];
#pragma unroll
  for (int d = 1; d < 64; d <<= 1) { sum += __shfl_xor(sum, d); cnt += __shfl_xor(cnt, d); }
  int w = tid >> 6;
  if ((tid & 63) == 0) { sS[w] = sum; sC[w] = cnt; }
  __syncthreads();
  if (tid == 0) {
    float s = 0.f, c = 0.f;
    for (int i = 0; i < 4; ++i) { s += sS[i]; c += sC[i]; }
    logps[blockIdx.x] = s / c;
  }
}

__global__ void finalk(const float* __restrict__ logps, const int* __restrict__ pref,
                       float* __restrict__ out) {
  if (threadIdx.x == 0 && blockIdx.x == 0) {
    float acc = 0.f;
    for (int b = 0; b < 4; ++b) {
      float lr = logps[b] - logps[4 + b];   // policy - ref
      float z = BETA * lr;
      float sig = 1.f / (1.f + __expf(-z));
      acc += (pref[b] != 0) ? (1.f - sig) : sig;
    }
    out[0] = acc * 0.25f;
  }
}

extern "C" void kernel_launch(void* const* d_in, const int* in_sizes, int n_in,
                              void* d_out, int out_size, void* d_ws, size_t ws_size,
                              hipStream_t stream) {
  const float* x    = (const float*)d_in[0];
  const float* rx   = (const float*)d_in[1];
  const int*   y    = (const int*)d_in[2];
  const int*   pref = (const int*)d_in[3];
  const float* W    = (const float*)d_in[4];
  const float* rW   = (const float*)d_in[5];
  float* out = (float*)d_out;

  char* ws = (char*)d_ws;
  const size_t SZ_X = (size_t)MROWS * KDIM * 2;        // 8,388,608
  const size_t SZ_W = (size_t)NVOCAB * KDIM * 2;       // 65,536,000
  __hip_bfloat16* xb   = (__hip_bfloat16*)(ws);
  __hip_bfloat16* rxb  = (__hip_bfloat16*)(ws + SZ_X);
  __hip_bfloat16* Wb   = (__hip_bfloat16*)(ws + 2 * SZ_X);
  __hip_bfloat16* rWb  = (__hip_bfloat16*)(ws + 2 * SZ_X + SZ_W);
  float2* partials = (float2*)(ws + 2 * SZ_X + 2 * SZ_W);
  float*  tgt      = (float*)(ws + 2 * SZ_X + 2 * SZ_W + (size_t)2 * NTILES * MROWS * 8);
  float*  logps    = (float*)(ws + 2 * SZ_X + 2 * SZ_W + (size_t)2 * NTILES * MROWS * 8 + 2 * MROWS * 4);

  cvt_all<<<dim3(2048), 256, 0, stream>>>((const float4*)x, (const float4*)rx,
                                          (const float4*)W, (const float4*)rW,
                                          (uint4*)xb, (uint4*)rxb, (uint4*)Wb, (uint4*)rWb);

  gemm_lse<<<dim3(2000, 2), 512, 0, stream>>>(xb, rxb, Wb, rWb, y, partials, tgt);
  rowred<<<dim3(8), 256, 0, stream>>>(partials, tgt, y, logps);
  finalk<<<dim3(1), 64, 0, stream>>>(logps, pref, out);
}